// Round 17
// baseline (178.765 us; speedup 1.0000x reference)
//
#include <hip/hip_runtime.h>

typedef unsigned short u16;
typedef unsigned int u32;
typedef __attribute__((ext_vector_type(8))) __bf16 bf16x8;
typedef __attribute__((ext_vector_type(4))) float f32x4;
typedef __attribute__((ext_vector_type(8))) unsigned short u16x8;
typedef __attribute__((ext_vector_type(4))) unsigned int u32x4;

typedef const __attribute__((address_space(1))) u32 gu32;
typedef __attribute__((address_space(3))) u32 lu32;

// fp32 -> bf16 round-to-nearest-even
__device__ __forceinline__ u16 f2b(float f) {
  u32 u = __builtin_bit_cast(u32, f);
  u32 r = u + 0x7fffu + ((u >> 16) & 1u);
  return (u16)(r >> 16);
}

// packed fp32 pair -> bf16 pair (RNE), lo in [15:0]
__device__ __forceinline__ u32 pk2(float lo, float hi) {
  u32 d;
  asm("v_cvt_pk_bf16_f32 %0, %1, %2" : "=v"(d) : "v"(lo), "v"(hi));
  return d;
}

// two f32x4 -> one bf16x8 (elements 0..3 from a, 4..7 from b)
__device__ __forceinline__ bf16x8 pack8(f32x4 a, f32x4 b) {
  u32x4 u;
  u[0] = pk2(a[0], a[1]);
  u[1] = pk2(a[2], a[3]);
  u[2] = pk2(b[0], b[1]);
  u[3] = pk2(b[2], b[3]);
  return __builtin_bit_cast(bf16x8, u);
}

__device__ __forceinline__ bf16x8 ld8(const u16* p) {
  return __builtin_bit_cast(bf16x8, *(const u16x8*)p);
}

__device__ __forceinline__ void gll16(const void* g, void* l) {
  __builtin_amdgcn_global_load_lds((gu32*)g, (lu32*)l, 16, 0, 0);
}

__device__ __forceinline__ f32x4 mfma16(bf16x8 a, bf16x8 b, f32x4 c) {
  return __builtin_amdgcn_mfma_f32_16x16x32_bf16(a, b, c, 0, 0, 0);
}

// ---------------- transpose+convert BOTH weights in one launch ----------------
// blocks x<96: w_attn [1024][3072] -> watT [3072][1024]; x>=96: w_o -> woT.
__global__ void k_tr2(const float* __restrict__ in0, u16* __restrict__ out0,
                      const float* __restrict__ in1, u16* __restrict__ out1) {
  __shared__ u16 tile[32][33];
  int bxr = blockIdx.x;
  const float* in;
  u16* out;
  int C, bx;
  if (bxr < 96) {
    in = in0; out = out0; C = 3072; bx = bxr * 32;
  } else {
    in = in1; out = out1; C = 1024; bx = (bxr - 96) * 32;
  }
  const int R = 1024;
  int by = blockIdx.y * 32;  // along R
  int tx = threadIdx.x, ty = threadIdx.y;  // (32, 8)
#pragma unroll
  for (int i = 0; i < 32; i += 8)
    tile[ty + i][tx] = f2b(in[(size_t)(by + ty + i) * C + bx + tx]);
  __syncthreads();
#pragma unroll
  for (int i = 0; i < 32; i += 8)
    out[(size_t)(bx + ty + i) * R + by + tx] = tile[tx][ty + i];
}

// ---------------- GEMM: A[M][1024] * B^T (B given as [N][1024]), 128x128 tile ----------------
// R11: counted-vmcnt 2-buffer pipeline. R12: T2 LDS swizzle. R16: T1 XCD block swizzle.
// R17 (EPI=0 only): A READ DIRECTLY AS F32 (the raw x input) -- conversion fused into
// staging, k_cvt kernel deleted (-64 MB HBM round-trip). A-side is reg-staged:
//   top of iter kt: issue 4x global_load_dwordx4 f32 for tile kt+2 (latency spans iter)
//   tail: BG(kt+2) gll16 x2 -> vmcnt(2) [forces B(kt+1)+A(kt+2), leaves B(kt+2) flying]
//         -> 8x v_cvt_pk -> 2x ds_write_b128 into the just-freed buffer.
//   lgkmcnt(0) before the top barrier makes A-writes visible one iter before readers.
// LDS layout/swizzle identical to the gll16 path (write slot lane&3 <- global chunk
// schunk), so the read side (rsw) is unchanged. EPI=1 keeps the pure-gll16 loop.
// EPI=0: scatter bf16 into q/k [B=4][H=16][T=2048][64] and V TRANSPOSED [B][H][64][T=2048].
//        q is stored PRE-SCALED by csc = 1/sqrt(64)*log2(e).
// EPI=1: fp32 out [M][1024]
template <int EPI>
__global__ __launch_bounds__(256) void k_gemm(const void* __restrict__ Ap,
                                              const u16* __restrict__ B,
                                              void* __restrict__ Cp) {
  const int K = 1024;
  const int NT = 32;  // K / 32
  __shared__ __align__(16) u16 As[2][128 * 32];
  __shared__ __align__(16) u16 Bs[2][128 * 32];
  int tid = threadIdx.x;
  int lane = tid & 63, wid = tid >> 6;
  int wr = wid >> 1, wc = wid & 1;

  // T1 XCD swizzle: contiguous chunk of remapped ids per XCD residue
  int nwgx = gridDim.x;
  int bid = blockIdx.y * nwgx + blockIdx.x;
  int cpx = (nwgx * gridDim.y) >> 3;  // nwg / 8 (both grids divisible by 8)
  int sb = (bid & 7) * cpx + (bid >> 3);
  int m0 = (sb / nwgx) * 128, n0 = (sb % nwgx) * 128;

  int r = lane & 15, qq = lane >> 4;

  // staging: pre-swizzled global chunk so LDS slot (lane&3) yields swizzled layout
  int schunk = (lane & 3) ^ ((lane >> 3) & 3);
  int arow = wid * 32 + (lane >> 2);
  const u16* Bg0 = B + (size_t)(n0 + arow) * K + schunk * 8;
  int sl0 = (wid * 32) * 32;            // this wave's staging rows (0..15)
  int sl1 = sl0 + 16 * 32;              // rows 16..31
  int rsw = (qq ^ ((r >> 1) & 3)) * 8;  // read-side swizzled slot (lane-constant)
  int awo = sl0 + (lane >> 2) * 32 + (lane & 3) * 8;  // A ds_write offset (elems)

  f32x4 acc[4][4] = {};

#define BG(buf, k0)                              \
  do {                                           \
    gll16(Bg0 + (k0), &Bs[buf][sl0]);            \
    gll16(Bg0 + 16 * K + (k0), &Bs[buf][sl1]);   \
  } while (0)

  if constexpr (EPI == 0) {
    const float* Af = (const float*)Ap;
    const float* Agf0 = Af + (size_t)(m0 + arow) * K + schunk * 8;
    const float* Agf1 = Agf0 + (size_t)16 * K;
    float4 av0, av1, av2, av3;

#define AISSUE(k0)                               \
  do {                                           \
    av0 = *(const float4*)(Agf0 + (k0));         \
    av1 = *(const float4*)(Agf0 + (k0) + 4);     \
    av2 = *(const float4*)(Agf1 + (k0));         \
    av3 = *(const float4*)(Agf1 + (k0) + 4);     \
  } while (0)
#define AWRITE(buf)                                            \
  do {                                                         \
    u32x4 w0, w1;                                              \
    w0[0] = pk2(av0.x, av0.y); w0[1] = pk2(av0.z, av0.w);      \
    w0[2] = pk2(av1.x, av1.y); w0[3] = pk2(av1.z, av1.w);      \
    w1[0] = pk2(av2.x, av2.y); w1[1] = pk2(av2.z, av2.w);      \
    w1[2] = pk2(av3.x, av3.y); w1[3] = pk2(av3.z, av3.w);      \
    *(u32x4*)&As[buf][awo] = w0;                               \
    *(u32x4*)&As[buf][awo + 16 * 32] = w1;                     \
  } while (0)

    // prologue: tiles 0 and 1
    AISSUE(0);
    BG(0, 0);
    asm volatile("s_waitcnt vmcnt(2)" ::: "memory");  // A(0) landed; B(0) may fly
    AWRITE(0);
    AISSUE(32);
    BG(1, 32);
    asm volatile("s_waitcnt vmcnt(2)" ::: "memory");  // forces B(0)+A(1); B(1) flies
    AWRITE(1);

    for (int kt = 0; kt < NT; ++kt) {
      int cur = kt & 1;
      if (kt + 2 < NT) AISSUE((kt + 2) * 32);  // regs only; latency spans the iter
      if (kt == NT - 1) asm volatile("s_waitcnt vmcnt(0)" ::: "memory");
      asm volatile("s_waitcnt lgkmcnt(0)" ::: "memory");  // own A ds_writes drained
      __builtin_amdgcn_s_barrier();  // tile kt (B gll + A writes) visible

      bf16x8 af[4], bfr[4];
#pragma unroll
      for (int m = 0; m < 4; ++m)
        af[m] = ld8(&As[cur][(wr * 64 + m * 16 + r) * 32 + rsw]);
#pragma unroll
      for (int n = 0; n < 4; ++n)
        bfr[n] = ld8(&Bs[cur][(wc * 64 + n * 16 + r) * 32 + rsw]);
      asm volatile("s_waitcnt lgkmcnt(0)" ::: "memory");
      __builtin_amdgcn_sched_barrier(0);
      __builtin_amdgcn_s_barrier();  // all waves done reading buf cur

      if (kt + 2 < NT) {
        BG(cur, (kt + 2) * 32);
        asm volatile("s_waitcnt vmcnt(2)" ::: "memory");  // B(kt+1)+A(kt+2) landed
        AWRITE(cur);
      }

#pragma unroll
      for (int m = 0; m < 4; ++m)
#pragma unroll
        for (int n = 0; n < 4; ++n) acc[m][n] = mfma16(af[m], bfr[n], acc[m][n]);
    }
#undef AISSUE
#undef AWRITE
  } else {
    const u16* Ab = (const u16*)Ap;
    const u16* Ag0 = Ab + (size_t)(m0 + arow) * K + schunk * 8;

#define GSTAGE(buf, k0)                          \
  do {                                           \
    gll16(Ag0 + (k0), &As[buf][sl0]);            \
    gll16(Ag0 + 16 * K + (k0), &As[buf][sl1]);   \
    BG(buf, k0);                                 \
  } while (0)

    GSTAGE(0, 0);
    GSTAGE(1, 32);

    for (int kt = 0; kt < NT; ++kt) {
      int cur = kt & 1;
      if (kt + 1 < NT)
        asm volatile("s_waitcnt vmcnt(4)" ::: "memory");  // kt landed, kt+1 in flight
      else
        asm volatile("s_waitcnt vmcnt(0)" ::: "memory");  // final tile
      __builtin_amdgcn_s_barrier();  // raw: no vmcnt drain

      bf16x8 af[4], bfr[4];
#pragma unroll
      for (int m = 0; m < 4; ++m)
        af[m] = ld8(&As[cur][(wr * 64 + m * 16 + r) * 32 + rsw]);
#pragma unroll
      for (int n = 0; n < 4; ++n)
        bfr[n] = ld8(&Bs[cur][(wc * 64 + n * 16 + r) * 32 + rsw]);
      asm volatile("s_waitcnt lgkmcnt(0)" ::: "memory");
      __builtin_amdgcn_sched_barrier(0);
      __builtin_amdgcn_s_barrier();  // all waves done reading buf cur

      if (kt + 2 < NT) GSTAGE(cur, (kt + 2) * 32);

#pragma unroll
      for (int m = 0; m < 4; ++m)
#pragma unroll
        for (int n = 0; n < 4; ++n) acc[m][n] = mfma16(af[m], bfr[n], acc[m][n]);
    }
#undef GSTAGE
  }
#undef BG

  if constexpr (EPI == 0) {
    u16* qkv = (u16*)Cp;
#pragma unroll
    for (int m = 0; m < 4; ++m) {
      int gr = m0 + wr * 64 + m * 16 + qq * 4;
      int b = gr >> 11, t0 = gr & 2047;
#pragma unroll
      for (int n = 0; n < 4; ++n) {
        int gc = n0 + wc * 64 + n * 16 + r;
        int which = gc >> 10, rem = gc & 1023;
        int hh = rem >> 6, d = rem & 63;
        if (which == 2) {
          // V^T: [(b*16+hh)*64 + d][2048] ; acc i-index is t (contiguous) -> one 8B store
          u16* dst = qkv + (size_t)2 * 8388608u +
                     ((size_t)((b * 16 + hh) * 64 + d)) * 2048 + t0;
          u32 p0 = pk2(acc[m][n][0], acc[m][n][1]);
          u32 p1 = pk2(acc[m][n][2], acc[m][n][3]);
          *(uint2*)dst = make_uint2(p0, p1);
        } else {
          // q (which==0) pre-scaled by csc; k (which==1) raw
          float sc = (which == 0) ? 0.18033688011112042f : 1.0f;
          u16* dst = qkv + (size_t)which * 8388608u +
                     ((size_t)((b * 16 + hh) * 2048 + t0)) * 64 + d;
#pragma unroll
          for (int i = 0; i < 4; ++i) dst[(size_t)i * 64] = f2b(acc[m][n][i] * sc);
        }
      }
    }
  } else {
    float* out = (float*)Cp;
#pragma unroll
    for (int m = 0; m < 4; ++m) {
      int gr = m0 + wr * 64 + m * 16 + qq * 4;
#pragma unroll
      for (int n = 0; n < 4; ++n) {
        int gc = n0 + wc * 64 + n * 16 + r;
#pragma unroll
        for (int i = 0; i < 4; ++i) out[(size_t)(gr + i) * 1024 + gc] = acc[m][n][i];
      }
    }
  }
}

// ---------------- flash attention (in-WG split-KV x2, 8 waves, pair-fused) ----------------
// R13 structure (best measured: attn 83.4 us), verbatim.
// WG = 512 thr = 8 waves over ONE 128-row q-block; group A (waves 0-3) even 64-key
// tiles, group B (waves 4-7) odd tiles, private online (m,l,acc); pair-fused (15-p, p)
// -> every WG runs exactly 17 pair-iterations + 2 merges. Grid 512 WGs = 2 WGs/CU
// (64 KB LDS) = 4 waves/SIMD. Lane-aligned exact flash merge via LDS.
__global__ __launch_bounds__(512) void k_attn(const u16* __restrict__ Qm,
                                              const u16* __restrict__ Km,
                                              const u16* __restrict__ VTm,
                                              u16* __restrict__ Y) {
  int bi = blockIdx.x;
  int p = bi >> 6;   // 0..7 pair id
  int bh = bi & 63;  // bi%8 = bh%8 -> head pinned to one XCD residue
  int b = bh >> 4, h = bh & 15;
  int tid = threadIdx.x, lane = tid & 63, w = tid >> 6;
  int g = w >> 2, wl = w & 3;  // KV-split group, wave-in-group
  int r = lane & 15, qq = lane >> 4;
  const size_t base = (size_t)bh * (2048 * 64);

  __shared__ __align__(16) u16 Kt[2][2][64 * 64];  // [parity][group][key][64], fk-swizzled
  __shared__ __align__(16) u16 Vt[2][2][64 * 64];  // [parity][group][d][64 keys], fv-swizzled

  // staging constants: wave wl stages rows wl*16..wl*16+15 of its GROUP's tile
  int srow = lane >> 3;                      // 0..7 within a slab
  int kch0 = (lane & 7) ^ (srow & 3);        // slab c=0: fk = (srow&3)|0
  int kch1 = (lane & 7) ^ ((srow & 3) | 4);  // slab c=1: row bit3=1 -> fk bit2=1
  int vch = (lane & 7) ^ srow;               // fv = row&7 = srow
  const u16* Kg = Km + base;
  const u16* Vg = VTm + base;

  // read-side constants
  int ar = 8 * (r >> 2) + (r & 3);            // A-fragment row offset
  int fkl = (r & 3) | (((r >> 2) & 1) << 2);  // fk(knt+ar), knt-independent
  int ks0 = ((qq ^ fkl)) * 8, ks1 = ((qq ^ fkl) ^ 4) * 8;
  int fvl = r & 7;
  int vs0 = ((qq ^ fvl)) * 8, vs1 = ((qq ^ fvl) ^ 4) * 8;

#define STAGE(par, j0n)                                                                 \
  do {                                                                                  \
    gll16(Kg + (size_t)((j0n) + wl * 16 + srow) * 64 + kch0 * 8,                        \
          &Kt[par][g][(wl * 16) * 64]);                                                 \
    gll16(Kg + (size_t)((j0n) + wl * 16 + 8 + srow) * 64 + kch1 * 8,                    \
          &Kt[par][g][(wl * 16 + 8) * 64]);                                             \
    gll16(Vg + (size_t)(wl * 16 + srow) * 2048 + (j0n) + vch * 8,                       \
          &Vt[par][g][(wl * 16) * 64]);                                                 \
    gll16(Vg + (size_t)(wl * 16 + 8 + srow) * 2048 + (j0n) + vch * 8,                   \
          &Vt[par][g][(wl * 16 + 8) * 64]);                                             \
  } while (0)

  for (int ph = 0; ph < 2; ++ph) {
    int qb = (ph == 0) ? (15 - p) : p;
    int qb0 = qb * 128;
    int q0w = qb0 + wl * 32;  // this wave's first q row

    // Q fragments (B-operand): q rows m*16+r, d-slices kc*32+qq*8 (q pre-scaled by csc)
    bf16x8 qf[2][2];
#pragma unroll
    for (int m = 0; m < 2; ++m)
#pragma unroll
      for (int kc = 0; kc < 2; ++kc)
        qf[m][kc] = ld8(Qm + base + (size_t)(q0w + m * 16 + r) * 64 + kc * 32 + qq * 8);

    f32x4 acc[2][4] = {};
    float m_run[2] = {-1e30f, -1e30f};
    float l_run[2] = {0.f, 0.f};
    int npairs = qb + 1;  // tile pairs (2qb+2 tiles split A=even B=odd)

    STAGE(0, g << 6);  // pair 0: group g's tile at j0 = g*64
    __syncthreads();

    for (int t2 = 0; t2 < npairs; ++t2) {
      int j0 = (t2 << 7) + (g << 6);  // this group's tile
      int cur = t2 & 1;
      bool active = (j0 <= q0w + 31);  // wave-uniform
      f32x4 s[4][2];
      bf16x8 vfr[4][2];

      if (active) {
        // S = K . Q^T with JIT kf reads from LDS
        __builtin_amdgcn_s_setprio(1);
#pragma unroll
        for (int nt = 0; nt < 4; ++nt) {
          int knt = 32 * (nt >> 1) + 4 * (nt & 1);
          const u16* kb_ = &Kt[cur][g][(knt + ar) * 64];
          bf16x8 k0 = ld8(kb_ + ks0);
          bf16x8 k1 = ld8(kb_ + ks1);
#pragma unroll
          for (int m = 0; m < 2; ++m) {
            f32x4 z = {};
            s[nt][m] = mfma16(k1, qf[m][1], mfma16(k0, qf[m][0], z));
          }
        }
        // bulk V^T fragment reads (consumed at PV; issued before STAGE on purpose)
#pragma unroll
        for (int n = 0; n < 4; ++n) {
          const u16* vb_ = &Vt[cur][g][(n * 16 + r) * 64];
          vfr[n][0] = ld8(vb_ + vs0);
          vfr[n][1] = ld8(vb_ + vs1);
        }
        __builtin_amdgcn_s_setprio(0);
      }

      // stage NEXT pair: issued after this tile's LDS reads; flies under softmax+PV
      if (t2 + 1 < npairs) STAGE((t2 + 1) & 1, ((t2 + 1) << 7) + (g << 6));

      if (active) {
        // causal mask on diagonal tiles only (q pre-scaled -> no scale op)
        bool nm = (j0 + 63 > q0w);
        if (nm) {
#pragma unroll
          for (int nt = 0; nt < 4; ++nt) {
            int kb = j0 + 32 * (nt >> 1) + 4 * (nt & 1) + 8 * qq;
#pragma unroll
            for (int m = 0; m < 2; ++m) {
              int qg = q0w + m * 16 + r;
#pragma unroll
              for (int i = 0; i < 4; ++i)
                s[nt][m][i] = (kb + i <= qg) ? s[nt][m][i] : -1e30f;
            }
          }
        }

        // row max: 15 in-lane fmax + 2 shfl rounds across qq groups
        float tm[2];
#pragma unroll
        for (int m = 0; m < 2; ++m) {
          float t0 = fmaxf(fmaxf(s[0][m][0], s[0][m][1]), fmaxf(s[0][m][2], s[0][m][3]));
          float t1 = fmaxf(fmaxf(s[1][m][0], s[1][m][1]), fmaxf(s[1][m][2], s[1][m][3]));
          float t2f = fmaxf(fmaxf(s[2][m][0], s[2][m][1]), fmaxf(s[2][m][2], s[2][m][3]));
          float t3 = fmaxf(fmaxf(s[3][m][0], s[3][m][1]), fmaxf(s[3][m][2], s[3][m][3]));
          float t = fmaxf(fmaxf(t0, t1), fmaxf(t2f, t3));
          t = fmaxf(t, __shfl_xor(t, 16));
          t = fmaxf(t, __shfl_xor(t, 32));
          tm[m] = t;
        }

        // rescale only if the running max grew
        int grow = (tm[0] > m_run[0]) | (tm[1] > m_run[1]);
        if (__any(grow)) {
#pragma unroll
          for (int m = 0; m < 2; ++m) {
            float mn = fmaxf(m_run[m], tm[m]);
            float corr = __builtin_amdgcn_exp2f(m_run[m] - mn);
            m_run[m] = mn;
            l_run[m] *= corr;
#pragma unroll
            for (int i = 0; i < 4; ++i) {
              float c = __shfl(corr, qq * 4 + i);
#pragma unroll
              for (int n = 0; n < 4; ++n) acc[m][n][i] *= c;
            }
          }
        }

        // P = exp2(S - m) via raw v_exp_f32; per-lane partial row sums
#pragma unroll
        for (int m = 0; m < 2; ++m) {
          float ls = 0.f;
#pragma unroll
          for (int nt = 0; nt < 4; ++nt)
#pragma unroll
            for (int i = 0; i < 4; ++i) {
              float e = __builtin_amdgcn_exp2f(s[nt][m][i] - m_run[m]);
              s[nt][m][i] = e;
              ls += e;
            }
          l_run[m] += ls;
        }

        // PV: P packs straight into A-fragments in-lane; vfr already in regs
        __builtin_amdgcn_s_setprio(1);
#pragma unroll
        for (int m = 0; m < 2; ++m) {
          bf16x8 pa0 = pack8(s[0][m], s[1][m]);  // keys qq*8+0..7
          bf16x8 pa1 = pack8(s[2][m], s[3][m]);  // keys 32+qq*8+0..7
#pragma unroll
          for (int n = 0; n < 4; ++n) acc[m][n] = mfma16(pa0, vfr[n][0], acc[m][n]);
#pragma unroll
          for (int n = 0; n < 4; ++n) acc[m][n] = mfma16(pa1, vfr[n][1], acc[m][n]);
        }
        __builtin_amdgcn_s_setprio(0);
      }

      __syncthreads();  // drains next-pair stage + protects buffer reuse
    }

    // per-wave: reduce row-sum partials across qq groups
    float lfin[2];
#pragma unroll
    for (int m = 0; m < 2; ++m) {
      float l = l_run[m];
      l += __shfl_xor(l, 16);
      l += __shfl_xor(l, 32);
      lfin[m] = l;
    }

    // merge staging in (reused) Kt/Vt: m=0 half in Kt, m=1 half in Vt; strides 17/5
    // floats keep scalar LDS ops conflict-free. Lane-aligned: wave wl <-> wave wl+4.
    float* mgK = (float*)&Kt[0][0][0];  // acc m=0 (16 floats/lane) + ml (4 floats/lane)
    float* mgV = (float*)&Vt[0][0][0];  // acc m=1
    int offA = wl * 1104 + lane * 17;
    int offM = 4608 + wl * 320 + lane * 5;
    if (g == 1) {
#pragma unroll
      for (int n = 0; n < 4; ++n)
#pragma unroll
        for (int i = 0; i < 4; ++i) {
          mgK[offA + n * 4 + i] = acc[0][n][i];
          mgV[offA + n * 4 + i] = acc[1][n][i];
        }
      mgK[offM + 0] = m_run[0];
      mgK[offM + 1] = m_run[1];
      mgK[offM + 2] = lfin[0];
      mgK[offM + 3] = lfin[1];
    }
    __syncthreads();

    if (g == 0) {
      // exact flash combine: m = max(mA,mB); fX = e^{mX-m} / (lA e^{mA-m} + lB e^{mB-m})
      float fA[2], fB[2];
#pragma unroll
      for (int m = 0; m < 2; ++m) {
        float mB = mgK[offM + m];
        float lB = mgK[offM + 2 + m];
        float mM = fmaxf(m_run[m], mB);
        float cA = __builtin_amdgcn_exp2f(m_run[m] - mM);
        float cB = __builtin_amdgcn_exp2f(mB - mM);
        float inv = 1.0f / (lfin[m] * cA + lB * cB);
        fA[m] = cA * inv;
        fB[m] = cB * inv;
      }
#pragma unroll
      for (int m = 0; m < 2; ++m)
#pragma unroll
        for (int i = 0; i < 4; ++i) {
          float a = __shfl(fA[m], qq * 4 + i);  // factor for q = m*16 + qq*4 + i
          float bq = __shfl(fB[m], qq * 4 + i);
          float* mg = (m == 0) ? mgK : mgV;
#pragma unroll
          for (int n = 0; n < 4; ++n) {
            float o = acc[m][n][i] * a + mg[offA + n * 4 + i] * bq;
            Y[((size_t)(b * 2048 + q0w + m * 16 + qq * 4 + i)) * 1024 + h * 64 +
              n * 16 + r] = f2b(o);
          }
        }
    }
    __syncthreads();  // merge reads done before next phase's STAGE overwrites
  }
#undef STAGE
}

// ---------------- launch ----------------
extern "C" void kernel_launch(void* const* d_in, const int* in_sizes, int n_in,
                              void* d_out, int out_size, void* d_ws, size_t ws_size,
                              hipStream_t stream) {
  const float* x = (const float*)d_in[0];       // [4,2048,1024]
  const float* w_attn = (const float*)d_in[1];  // [1024,3072]
  const float* w_o = (const float*)d_in[2];     // [1024,1024]
  float* out = (float*)d_out;                   // [4,2048,1024]

  char* ws = (char*)d_ws;
  u16* watT = (u16*)(ws + 16777216);           // [3072][1024]         6,291,456 B
  u16* woT = (u16*)(ws + 23068672);            // [1024][1024]         2,097,152 B
  u16* qb = (u16*)(ws + 25165824);             // q [4][16][2048][64] 16,777,216 B
  u16* kb = (u16*)(ws + 41943040);             // k                   16,777,216 B
  u16* vb = (u16*)(ws + 58720256);             // V^T [4][16][64][2048] 16,777,216 B
  u16* yb = (u16*)(ws + 75497472);             // y [4][2048][1024]   16,777,216 B

  k_tr2<<<dim3(128, 32), dim3(32, 8), 0, stream>>>(w_attn, watT, w_o, woT);
  k_gemm<0><<<dim3(24, 64), 256, 0, stream>>>((const void*)x, watT, (void*)qb);
  k_attn<<<dim3(512), 512, 0, stream>>>(qb, kb, vb, yb);
  k_gemm<1><<<dim3(8, 64), 256, 0, stream>>>((const void*)yb, woT, (void*)out);
}

// Round 18
// 174.446 us; speedup vs baseline: 1.0248x; 1.0248x over previous
//
#include <hip/hip_runtime.h>

typedef unsigned short u16;
typedef unsigned int u32;
typedef __attribute__((ext_vector_type(8))) __bf16 bf16x8;
typedef __attribute__((ext_vector_type(4))) float f32x4;
typedef __attribute__((ext_vector_type(8))) unsigned short u16x8;
typedef __attribute__((ext_vector_type(4))) unsigned int u32x4;

typedef const __attribute__((address_space(1))) u32 gu32;
typedef __attribute__((address_space(3))) u32 lu32;

// fp32 -> bf16 round-to-nearest-even
__device__ __forceinline__ u16 f2b(float f) {
  u32 u = __builtin_bit_cast(u32, f);
  u32 r = u + 0x7fffu + ((u >> 16) & 1u);
  return (u16)(r >> 16);
}

// packed fp32 pair -> bf16 pair (RNE), lo in [15:0]
__device__ __forceinline__ u32 pk2(float lo, float hi) {
  u32 d;
  asm("v_cvt_pk_bf16_f32 %0, %1, %2" : "=v"(d) : "v"(lo), "v"(hi));
  return d;
}

// two f32x4 -> one bf16x8 (elements 0..3 from a, 4..7 from b)
__device__ __forceinline__ bf16x8 pack8(f32x4 a, f32x4 b) {
  u32x4 u;
  u[0] = pk2(a[0], a[1]);
  u[1] = pk2(a[2], a[3]);
  u[2] = pk2(b[0], b[1]);
  u[3] = pk2(b[2], b[3]);
  return __builtin_bit_cast(bf16x8, u);
}

__device__ __forceinline__ bf16x8 ld8(const u16* p) {
  return __builtin_bit_cast(bf16x8, *(const u16x8*)p);
}

__device__ __forceinline__ void gll16(const void* g, void* l) {
  __builtin_amdgcn_global_load_lds((gu32*)g, (lu32*)l, 16, 0, 0);
}

__device__ __forceinline__ f32x4 mfma16(bf16x8 a, bf16x8 b, f32x4 c) {
  return __builtin_amdgcn_mfma_f32_16x16x32_bf16(a, b, c, 0, 0, 0);
}

// ---------------- transpose+convert BOTH weights in one launch ----------------
// blocks x<96: w_attn [1024][3072] -> watT [3072][1024]; x>=96: w_o -> woT.
__global__ void k_tr2(const float* __restrict__ in0, u16* __restrict__ out0,
                      const float* __restrict__ in1, u16* __restrict__ out1) {
  __shared__ u16 tile[32][33];
  int bxr = blockIdx.x;
  const float* in;
  u16* out;
  int C, bx;
  if (bxr < 96) {
    in = in0; out = out0; C = 3072; bx = bxr * 32;
  } else {
    in = in1; out = out1; C = 1024; bx = (bxr - 96) * 32;
  }
  const int R = 1024;
  int by = blockIdx.y * 32;  // along R
  int tx = threadIdx.x, ty = threadIdx.y;  // (32, 8)
#pragma unroll
  for (int i = 0; i < 32; i += 8)
    tile[ty + i][tx] = f2b(in[(size_t)(by + ty + i) * C + bx + tx]);
  __syncthreads();
#pragma unroll
  for (int i = 0; i < 32; i += 8)
    out[(size_t)(bx + ty + i) * R + by + tx] = tile[tx][ty + i];
}

// ---------------- GEMM: A[M][1024] * B^T (B given as [N][1024]), 128x128 tile ----------------
// R11: counted-vmcnt 2-buffer pipeline. R12: T2 LDS swizzle. R16: T1 XCD block swizzle.
// R17: A read directly as f32 (k_cvt fused away); R18: FIX the R17 regression -- the
// tail had BG -> vmcnt(2) -> AWRITE -> MFMA, putting the MFMA block BEHIND a wait for
// B(kt+1) to land (a per-iteration load-latency stall; gemm0 83 -> 96.5 us). New tail:
// BG(kt+2) -> 16x MFMA -> sched_barrier(0) [pin] -> vmcnt(2) -> AWRITE(cur).
// MFMA issues immediately (R16 behavior); B(kt+1) retires during the MFMA block.
// Correctness: AWRITE(cur) targets the buffer whose readers finished at this iter's
// 2nd barrier; its ds_writes drain at next iter's top lgkmcnt(0)+barrier, one full
// iteration before their readers (kt+2). vmcnt accounting unchanged.
// EPI=0: scatter bf16 into q/k [B=4][H=16][T=2048][64] and V TRANSPOSED [B][H][64][T=2048].
//        q is stored PRE-SCALED by csc = 1/sqrt(64)*log2(e).
// EPI=1: fp32 out [M][1024] (pure-gll16 loop).
template <int EPI>
__global__ __launch_bounds__(256) void k_gemm(const void* __restrict__ Ap,
                                              const u16* __restrict__ B,
                                              void* __restrict__ Cp) {
  const int K = 1024;
  const int NT = 32;  // K / 32
  __shared__ __align__(16) u16 As[2][128 * 32];
  __shared__ __align__(16) u16 Bs[2][128 * 32];
  int tid = threadIdx.x;
  int lane = tid & 63, wid = tid >> 6;
  int wr = wid >> 1, wc = wid & 1;

  // T1 XCD swizzle: contiguous chunk of remapped ids per XCD residue
  int nwgx = gridDim.x;
  int bid = blockIdx.y * nwgx + blockIdx.x;
  int cpx = (nwgx * gridDim.y) >> 3;  // nwg / 8 (both grids divisible by 8)
  int sb = (bid & 7) * cpx + (bid >> 3);
  int m0 = (sb / nwgx) * 128, n0 = (sb % nwgx) * 128;

  int r = lane & 15, qq = lane >> 4;

  // staging: pre-swizzled global chunk so LDS slot (lane&3) yields swizzled layout
  int schunk = (lane & 3) ^ ((lane >> 3) & 3);
  int arow = wid * 32 + (lane >> 2);
  const u16* Bg0 = B + (size_t)(n0 + arow) * K + schunk * 8;
  int sl0 = (wid * 32) * 32;            // this wave's staging rows (0..15)
  int sl1 = sl0 + 16 * 32;              // rows 16..31
  int rsw = (qq ^ ((r >> 1) & 3)) * 8;  // read-side swizzled slot (lane-constant)
  int awo = sl0 + (lane >> 2) * 32 + (lane & 3) * 8;  // A ds_write offset (elems)

  f32x4 acc[4][4] = {};

#define BG(buf, k0)                              \
  do {                                           \
    gll16(Bg0 + (k0), &Bs[buf][sl0]);            \
    gll16(Bg0 + 16 * K + (k0), &Bs[buf][sl1]);   \
  } while (0)

  if constexpr (EPI == 0) {
    const float* Af = (const float*)Ap;
    const float* Agf0 = Af + (size_t)(m0 + arow) * K + schunk * 8;
    const float* Agf1 = Agf0 + (size_t)16 * K;
    float4 av0, av1, av2, av3;

#define AISSUE(k0)                               \
  do {                                           \
    av0 = *(const float4*)(Agf0 + (k0));         \
    av1 = *(const float4*)(Agf0 + (k0) + 4);     \
    av2 = *(const float4*)(Agf1 + (k0));         \
    av3 = *(const float4*)(Agf1 + (k0) + 4);     \
  } while (0)
#define AWRITE(buf)                                            \
  do {                                                         \
    u32x4 w0, w1;                                              \
    w0[0] = pk2(av0.x, av0.y); w0[1] = pk2(av0.z, av0.w);      \
    w0[2] = pk2(av1.x, av1.y); w0[3] = pk2(av1.z, av1.w);      \
    w1[0] = pk2(av2.x, av2.y); w1[1] = pk2(av2.z, av2.w);      \
    w1[2] = pk2(av3.x, av3.y); w1[3] = pk2(av3.z, av3.w);      \
    *(u32x4*)&As[buf][awo] = w0;                               \
    *(u32x4*)&As[buf][awo + 16 * 32] = w1;                     \
  } while (0)

    // prologue: tiles 0 and 1
    AISSUE(0);
    BG(0, 0);
    asm volatile("s_waitcnt vmcnt(2)" ::: "memory");  // A(0) landed; B(0) may fly
    AWRITE(0);
    AISSUE(32);
    BG(1, 32);
    asm volatile("s_waitcnt vmcnt(2)" ::: "memory");  // forces B(0)+A(1); B(1) flies
    AWRITE(1);

    for (int kt = 0; kt < NT; ++kt) {
      int cur = kt & 1;
      if (kt + 2 < NT) AISSUE((kt + 2) * 32);  // regs only; latency spans the iter
      if (kt == NT - 1) asm volatile("s_waitcnt vmcnt(0)" ::: "memory");
      asm volatile("s_waitcnt lgkmcnt(0)" ::: "memory");  // own A ds_writes drained
      __builtin_amdgcn_s_barrier();  // tile kt (B gll + A writes) visible

      bf16x8 af[4], bfr[4];
#pragma unroll
      for (int m = 0; m < 4; ++m)
        af[m] = ld8(&As[cur][(wr * 64 + m * 16 + r) * 32 + rsw]);
#pragma unroll
      for (int n = 0; n < 4; ++n)
        bfr[n] = ld8(&Bs[cur][(wc * 64 + n * 16 + r) * 32 + rsw]);
      asm volatile("s_waitcnt lgkmcnt(0)" ::: "memory");
      __builtin_amdgcn_sched_barrier(0);
      __builtin_amdgcn_s_barrier();  // all waves done reading buf cur

      if (kt + 2 < NT) BG(cur, (kt + 2) * 32);  // fire-and-forget

      // MFMA first (not blocked by any vmcnt) ...
#pragma unroll
      for (int m = 0; m < 4; ++m)
#pragma unroll
        for (int n = 0; n < 4; ++n) acc[m][n] = mfma16(af[m], bfr[n], acc[m][n]);
      __builtin_amdgcn_sched_barrier(0);  // pin MFMA ahead of the wait below

      // ... then land A(kt+2) (+B(kt+1)) and write A into the freed buffer
      if (kt + 2 < NT) {
        asm volatile("s_waitcnt vmcnt(2)" ::: "memory");  // B(kt+1)+A(kt+2) landed
        AWRITE(cur);
      }
    }
#undef AISSUE
#undef AWRITE
  } else {
    const u16* Ab = (const u16*)Ap;
    const u16* Ag0 = Ab + (size_t)(m0 + arow) * K + schunk * 8;

#define GSTAGE(buf, k0)                          \
  do {                                           \
    gll16(Ag0 + (k0), &As[buf][sl0]);            \
    gll16(Ag0 + 16 * K + (k0), &As[buf][sl1]);   \
    BG(buf, k0);                                 \
  } while (0)

    GSTAGE(0, 0);
    GSTAGE(1, 32);

    for (int kt = 0; kt < NT; ++kt) {
      int cur = kt & 1;
      if (kt + 1 < NT)
        asm volatile("s_waitcnt vmcnt(4)" ::: "memory");  // kt landed, kt+1 in flight
      else
        asm volatile("s_waitcnt vmcnt(0)" ::: "memory");  // final tile
      __builtin_amdgcn_s_barrier();  // raw: no vmcnt drain

      bf16x8 af[4], bfr[4];
#pragma unroll
      for (int m = 0; m < 4; ++m)
        af[m] = ld8(&As[cur][(wr * 64 + m * 16 + r) * 32 + rsw]);
#pragma unroll
      for (int n = 0; n < 4; ++n)
        bfr[n] = ld8(&Bs[cur][(wc * 64 + n * 16 + r) * 32 + rsw]);
      asm volatile("s_waitcnt lgkmcnt(0)" ::: "memory");
      __builtin_amdgcn_sched_barrier(0);
      __builtin_amdgcn_s_barrier();  // all waves done reading buf cur

      if (kt + 2 < NT) GSTAGE(cur, (kt + 2) * 32);

#pragma unroll
      for (int m = 0; m < 4; ++m)
#pragma unroll
        for (int n = 0; n < 4; ++n) acc[m][n] = mfma16(af[m], bfr[n], acc[m][n]);
    }
#undef GSTAGE
  }
#undef BG

  if constexpr (EPI == 0) {
    u16* qkv = (u16*)Cp;
#pragma unroll
    for (int m = 0; m < 4; ++m) {
      int gr = m0 + wr * 64 + m * 16 + qq * 4;
      int b = gr >> 11, t0 = gr & 2047;
#pragma unroll
      for (int n = 0; n < 4; ++n) {
        int gc = n0 + wc * 64 + n * 16 + r;
        int which = gc >> 10, rem = gc & 1023;
        int hh = rem >> 6, d = rem & 63;
        if (which == 2) {
          // V^T: [(b*16+hh)*64 + d][2048] ; acc i-index is t (contiguous) -> one 8B store
          u16* dst = qkv + (size_t)2 * 8388608u +
                     ((size_t)((b * 16 + hh) * 64 + d)) * 2048 + t0;
          u32 p0 = pk2(acc[m][n][0], acc[m][n][1]);
          u32 p1 = pk2(acc[m][n][2], acc[m][n][3]);
          *(uint2*)dst = make_uint2(p0, p1);
        } else {
          // q (which==0) pre-scaled by csc; k (which==1) raw
          float sc = (which == 0) ? 0.18033688011112042f : 1.0f;
          u16* dst = qkv + (size_t)which * 8388608u +
                     ((size_t)((b * 16 + hh) * 2048 + t0)) * 64 + d;
#pragma unroll
          for (int i = 0; i < 4; ++i) dst[(size_t)i * 64] = f2b(acc[m][n][i] * sc);
        }
      }
    }
  } else {
    float* out = (float*)Cp;
#pragma unroll
    for (int m = 0; m < 4; ++m) {
      int gr = m0 + wr * 64 + m * 16 + qq * 4;
#pragma unroll
      for (int n = 0; n < 4; ++n) {
        int gc = n0 + wc * 64 + n * 16 + r;
#pragma unroll
        for (int i = 0; i < 4; ++i) out[(size_t)(gr + i) * 1024 + gc] = acc[m][n][i];
      }
    }
  }
}

// ---------------- flash attention (in-WG split-KV x2, 8 waves, pair-fused) ----------------
// R13 structure (best measured: attn 83.4 us), verbatim.
// WG = 512 thr = 8 waves over ONE 128-row q-block; group A (waves 0-3) even 64-key
// tiles, group B (waves 4-7) odd tiles, private online (m,l,acc); pair-fused (15-p, p)
// -> every WG runs exactly 17 pair-iterations + 2 merges. Grid 512 WGs = 2 WGs/CU
// (64 KB LDS) = 4 waves/SIMD. Lane-aligned exact flash merge via LDS.
__global__ __launch_bounds__(512) void k_attn(const u16* __restrict__ Qm,
                                              const u16* __restrict__ Km,
                                              const u16* __restrict__ VTm,
                                              u16* __restrict__ Y) {
  int bi = blockIdx.x;
  int p = bi >> 6;   // 0..7 pair id
  int bh = bi & 63;  // bi%8 = bh%8 -> head pinned to one XCD residue
  int b = bh >> 4, h = bh & 15;
  int tid = threadIdx.x, lane = tid & 63, w = tid >> 6;
  int g = w >> 2, wl = w & 3;  // KV-split group, wave-in-group
  int r = lane & 15, qq = lane >> 4;
  const size_t base = (size_t)bh * (2048 * 64);

  __shared__ __align__(16) u16 Kt[2][2][64 * 64];  // [parity][group][key][64], fk-swizzled
  __shared__ __align__(16) u16 Vt[2][2][64 * 64];  // [parity][group][d][64 keys], fv-swizzled

  // staging constants: wave wl stages rows wl*16..wl*16+15 of its GROUP's tile
  int srow = lane >> 3;                      // 0..7 within a slab
  int kch0 = (lane & 7) ^ (srow & 3);        // slab c=0: fk = (srow&3)|0
  int kch1 = (lane & 7) ^ ((srow & 3) | 4);  // slab c=1: row bit3=1 -> fk bit2=1
  int vch = (lane & 7) ^ srow;               // fv = row&7 = srow
  const u16* Kg = Km + base;
  const u16* Vg = VTm + base;

  // read-side constants
  int ar = 8 * (r >> 2) + (r & 3);            // A-fragment row offset
  int fkl = (r & 3) | (((r >> 2) & 1) << 2);  // fk(knt+ar), knt-independent
  int ks0 = ((qq ^ fkl)) * 8, ks1 = ((qq ^ fkl) ^ 4) * 8;
  int fvl = r & 7;
  int vs0 = ((qq ^ fvl)) * 8, vs1 = ((qq ^ fvl) ^ 4) * 8;

#define STAGE(par, j0n)                                                                 \
  do {                                                                                  \
    gll16(Kg + (size_t)((j0n) + wl * 16 + srow) * 64 + kch0 * 8,                        \
          &Kt[par][g][(wl * 16) * 64]);                                                 \
    gll16(Kg + (size_t)((j0n) + wl * 16 + 8 + srow) * 64 + kch1 * 8,                    \
          &Kt[par][g][(wl * 16 + 8) * 64]);                                             \
    gll16(Vg + (size_t)(wl * 16 + srow) * 2048 + (j0n) + vch * 8,                       \
          &Vt[par][g][(wl * 16) * 64]);                                                 \
    gll16(Vg + (size_t)(wl * 16 + 8 + srow) * 2048 + (j0n) + vch * 8,                   \
          &Vt[par][g][(wl * 16 + 8) * 64]);                                             \
  } while (0)

  for (int ph = 0; ph < 2; ++ph) {
    int qb = (ph == 0) ? (15 - p) : p;
    int qb0 = qb * 128;
    int q0w = qb0 + wl * 32;  // this wave's first q row

    // Q fragments (B-operand): q rows m*16+r, d-slices kc*32+qq*8 (q pre-scaled by csc)
    bf16x8 qf[2][2];
#pragma unroll
    for (int m = 0; m < 2; ++m)
#pragma unroll
      for (int kc = 0; kc < 2; ++kc)
        qf[m][kc] = ld8(Qm + base + (size_t)(q0w + m * 16 + r) * 64 + kc * 32 + qq * 8);

    f32x4 acc[2][4] = {};
    float m_run[2] = {-1e30f, -1e30f};
    float l_run[2] = {0.f, 0.f};
    int npairs = qb + 1;  // tile pairs (2qb+2 tiles split A=even B=odd)

    STAGE(0, g << 6);  // pair 0: group g's tile at j0 = g*64
    __syncthreads();

    for (int t2 = 0; t2 < npairs; ++t2) {
      int j0 = (t2 << 7) + (g << 6);  // this group's tile
      int cur = t2 & 1;
      bool active = (j0 <= q0w + 31);  // wave-uniform
      f32x4 s[4][2];
      bf16x8 vfr[4][2];

      if (active) {
        // S = K . Q^T with JIT kf reads from LDS
        __builtin_amdgcn_s_setprio(1);
#pragma unroll
        for (int nt = 0; nt < 4; ++nt) {
          int knt = 32 * (nt >> 1) + 4 * (nt & 1);
          const u16* kb_ = &Kt[cur][g][(knt + ar) * 64];
          bf16x8 k0 = ld8(kb_ + ks0);
          bf16x8 k1 = ld8(kb_ + ks1);
#pragma unroll
          for (int m = 0; m < 2; ++m) {
            f32x4 z = {};
            s[nt][m] = mfma16(k1, qf[m][1], mfma16(k0, qf[m][0], z));
          }
        }
        // bulk V^T fragment reads (consumed at PV; issued before STAGE on purpose)
#pragma unroll
        for (int n = 0; n < 4; ++n) {
          const u16* vb_ = &Vt[cur][g][(n * 16 + r) * 64];
          vfr[n][0] = ld8(vb_ + vs0);
          vfr[n][1] = ld8(vb_ + vs1);
        }
        __builtin_amdgcn_s_setprio(0);
      }

      // stage NEXT pair: issued after this tile's LDS reads; flies under softmax+PV
      if (t2 + 1 < npairs) STAGE((t2 + 1) & 1, ((t2 + 1) << 7) + (g << 6));

      if (active) {
        // causal mask on diagonal tiles only (q pre-scaled -> no scale op)
        bool nm = (j0 + 63 > q0w);
        if (nm) {
#pragma unroll
          for (int nt = 0; nt < 4; ++nt) {
            int kb = j0 + 32 * (nt >> 1) + 4 * (nt & 1) + 8 * qq;
#pragma unroll
            for (int m = 0; m < 2; ++m) {
              int qg = q0w + m * 16 + r;
#pragma unroll
              for (int i = 0; i < 4; ++i)
                s[nt][m][i] = (kb + i <= qg) ? s[nt][m][i] : -1e30f;
            }
          }
        }

        // row max: 15 in-lane fmax + 2 shfl rounds across qq groups
        float tm[2];
#pragma unroll
        for (int m = 0; m < 2; ++m) {
          float t0 = fmaxf(fmaxf(s[0][m][0], s[0][m][1]), fmaxf(s[0][m][2], s[0][m][3]));
          float t1 = fmaxf(fmaxf(s[1][m][0], s[1][m][1]), fmaxf(s[1][m][2], s[1][m][3]));
          float t2f = fmaxf(fmaxf(s[2][m][0], s[2][m][1]), fmaxf(s[2][m][2], s[2][m][3]));
          float t3 = fmaxf(fmaxf(s[3][m][0], s[3][m][1]), fmaxf(s[3][m][2], s[3][m][3]));
          float t = fmaxf(fmaxf(t0, t1), fmaxf(t2f, t3));
          t = fmaxf(t, __shfl_xor(t, 16));
          t = fmaxf(t, __shfl_xor(t, 32));
          tm[m] = t;
        }

        // rescale only if the running max grew
        int grow = (tm[0] > m_run[0]) | (tm[1] > m_run[1]);
        if (__any(grow)) {
#pragma unroll
          for (int m = 0; m < 2; ++m) {
            float mn = fmaxf(m_run[m], tm[m]);
            float corr = __builtin_amdgcn_exp2f(m_run[m] - mn);
            m_run[m] = mn;
            l_run[m] *= corr;
#pragma unroll
            for (int i = 0; i < 4; ++i) {
              float c = __shfl(corr, qq * 4 + i);
#pragma unroll
              for (int n = 0; n < 4; ++n) acc[m][n][i] *= c;
            }
          }
        }

        // P = exp2(S - m) via raw v_exp_f32; per-lane partial row sums
#pragma unroll
        for (int m = 0; m < 2; ++m) {
          float ls = 0.f;
#pragma unroll
          for (int nt = 0; nt < 4; ++nt)
#pragma unroll
            for (int i = 0; i < 4; ++i) {
              float e = __builtin_amdgcn_exp2f(s[nt][m][i] - m_run[m]);
              s[nt][m][i] = e;
              ls += e;
            }
          l_run[m] += ls;
        }

        // PV: P packs straight into A-fragments in-lane; vfr already in regs
        __builtin_amdgcn_s_setprio(1);
#pragma unroll
        for (int m = 0; m < 2; ++m) {
          bf16x8 pa0 = pack8(s[0][m], s[1][m]);  // keys qq*8+0..7
          bf16x8 pa1 = pack8(s[2][m], s[3][m]);  // keys 32+qq*8+0..7
#pragma unroll
          for (int n = 0; n < 4; ++n) acc[m][n] = mfma16(pa0, vfr[n][0], acc[m][n]);
#pragma unroll
          for (int n = 0; n < 4; ++n) acc[m][n] = mfma16(pa1, vfr[n][1], acc[m][n]);
        }
        __builtin_amdgcn_s_setprio(0);
      }

      __syncthreads();  // drains next-pair stage + protects buffer reuse
    }

    // per-wave: reduce row-sum partials across qq groups
    float lfin[2];
#pragma unroll
    for (int m = 0; m < 2; ++m) {
      float l = l_run[m];
      l += __shfl_xor(l, 16);
      l += __shfl_xor(l, 32);
      lfin[m] = l;
    }

    // merge staging in (reused) Kt/Vt: m=0 half in Kt, m=1 half in Vt; strides 17/5
    // floats keep scalar LDS ops conflict-free. Lane-aligned: wave wl <-> wave wl+4.
    float* mgK = (float*)&Kt[0][0][0];  // acc m=0 (16 floats/lane) + ml (4 floats/lane)
    float* mgV = (float*)&Vt[0][0][0];  // acc m=1
    int offA = wl * 1104 + lane * 17;
    int offM = 4608 + wl * 320 + lane * 5;
    if (g == 1) {
#pragma unroll
      for (int n = 0; n < 4; ++n)
#pragma unroll
        for (int i = 0; i < 4; ++i) {
          mgK[offA + n * 4 + i] = acc[0][n][i];
          mgV[offA + n * 4 + i] = acc[1][n][i];
        }
      mgK[offM + 0] = m_run[0];
      mgK[offM + 1] = m_run[1];
      mgK[offM + 2] = lfin[0];
      mgK[offM + 3] = lfin[1];
    }
    __syncthreads();

    if (g == 0) {
      // exact flash combine: m = max(mA,mB); fX = e^{mX-m} / (lA e^{mA-m} + lB e^{mB-m})
      float fA[2], fB[2];
#pragma unroll
      for (int m = 0; m < 2; ++m) {
        float mB = mgK[offM + m];
        float lB = mgK[offM + 2 + m];
        float mM = fmaxf(m_run[m], mB);
        float cA = __builtin_amdgcn_exp2f(m_run[m] - mM);
        float cB = __builtin_amdgcn_exp2f(mB - mM);
        float inv = 1.0f / (lfin[m] * cA + lB * cB);
        fA[m] = cA * inv;
        fB[m] = cB * inv;
      }
#pragma unroll
      for (int m = 0; m < 2; ++m)
#pragma unroll
        for (int i = 0; i < 4; ++i) {
          float a = __shfl(fA[m], qq * 4 + i);  // factor for q = m*16 + qq*4 + i
          float bq = __shfl(fB[m], qq * 4 + i);
          float* mg = (m == 0) ? mgK : mgV;
#pragma unroll
          for (int n = 0; n < 4; ++n) {
            float o = acc[m][n][i] * a + mg[offA + n * 4 + i] * bq;
            Y[((size_t)(b * 2048 + q0w + m * 16 + qq * 4 + i)) * 1024 + h * 64 +
              n * 16 + r] = f2b(o);
          }
        }
    }
    __syncthreads();  // merge reads done before next phase's STAGE overwrites
  }
#undef STAGE
}

// ---------------- launch ----------------
extern "C" void kernel_launch(void* const* d_in, const int* in_sizes, int n_in,
                              void* d_out, int out_size, void* d_ws, size_t ws_size,
                              hipStream_t stream) {
  const float* x = (const float*)d_in[0];       // [4,2048,1024]
  const float* w_attn = (const float*)d_in[1];  // [1024,3072]
  const float* w_o = (const float*)d_in[2];     // [1024,1024]
  float* out = (float*)d_out;                   // [4,2048,1024]

  char* ws = (char*)d_ws;
  u16* watT = (u16*)(ws + 16777216);           // [3072][1024]         6,291,456 B
  u16* woT = (u16*)(ws + 23068672);            // [1024][1024]         2,097,152 B
  u16* qb = (u16*)(ws + 25165824);             // q [4][16][2048][64] 16,777,216 B
  u16* kb = (u16*)(ws + 41943040);             // k                   16,777,216 B
  u16* vb = (u16*)(ws + 58720256);             // V^T [4][16][64][2048] 16,777,216 B
  u16* yb = (u16*)(ws + 75497472);             // y [4][2048][1024]   16,777,216 B

  k_tr2<<<dim3(128, 32), dim3(32, 8), 0, stream>>>(w_attn, watT, w_o, woT);
  k_gemm<0><<<dim3(24, 64), 256, 0, stream>>>((const void*)x, watT, (void*)qb);
  k_attn<<<dim3(512), 512, 0, stream>>>(qb, kb, vb, yb);
  k_gemm<1><<<dim3(8, 64), 256, 0, stream>>>((const void*)yb, woT, (void*)out);
}